// Round 1
// baseline (739.996 us; speedup 1.0000x reference)
//
#include <hip/hip_runtime.h>
#include <cstddef>

#define B_ 16
#define CIN_ 256
#define H_ 32
#define W_ 32
#define HW_ 1024
#define COUT_ 256
#define DK_ 128
#define DV_ 128
#define NH_ 8
#define DKH_ 16
#define DVH_ 16
#define CCONV_ 128
#define QKVO_ 384

// ---------------- K1: qkv 1x1 conv == GEMM W[384,256] * X[256,1024] per image ----------------
__global__ __launch_bounds__(256) void qkv_kernel(
    const float* __restrict__ x, const float* __restrict__ qkv_w,
    const float* __restrict__ qkv_b, float* __restrict__ qkv)
{
    const int pt = blockIdx.x;        // 0..7   (128 pixels)
    const int ot = blockIdx.y;        // 0..5   (64 outputs)
    const int b  = blockIdx.z;        // 0..15
    const int tid = threadIdx.x;
    const int og = tid >> 5;          // 0..7
    const int pg = tid & 31;          // 0..31
    __shared__ float Ws[64 * 36];     // padded stride 36 -> conflict-free staging
    __shared__ float Xs[32 * 132];    // padded stride 132

    float acc[8][4];
#pragma unroll
    for (int i = 0; i < 8; ++i)
#pragma unroll
        for (int j = 0; j < 4; ++j) acc[i][j] = 0.f;

    const int o0 = ot * 64, p0 = pt * 128;

    for (int k0 = 0; k0 < CIN_; k0 += 32) {
        __syncthreads();
        {   // stage W tile: 64 rows x 32 k
            const int r = tid >> 2, c0 = (tid & 3) * 8;
            const float* src = qkv_w + (size_t)(o0 + r) * CIN_ + k0 + c0;
            *(float4*)&Ws[r * 36 + c0]     = *(const float4*)src;
            *(float4*)&Ws[r * 36 + c0 + 4] = *(const float4*)(src + 4);
        }
        {   // stage X tile: 32 k x 128 p
            const int kk = tid >> 3, c0 = (tid & 7) * 16;
            const float* src = x + ((size_t)b * CIN_ + k0 + kk) * HW_ + p0 + c0;
#pragma unroll
            for (int m = 0; m < 4; ++m)
                *(float4*)&Xs[kk * 132 + c0 + m * 4] = *(const float4*)(src + m * 4);
        }
        __syncthreads();
#pragma unroll 4
        for (int k = 0; k < 32; ++k) {
            float a[8];
#pragma unroll
            for (int i = 0; i < 8; ++i) a[i] = Ws[(og * 8 + i) * 36 + k];
            const float4 bb = *(const float4*)&Xs[k * 132 + pg * 4];
#pragma unroll
            for (int i = 0; i < 8; ++i) {
                acc[i][0] += a[i] * bb.x;
                acc[i][1] += a[i] * bb.y;
                acc[i][2] += a[i] * bb.z;
                acc[i][3] += a[i] * bb.w;
            }
        }
    }
#pragma unroll
    for (int i = 0; i < 8; ++i) {
        const int o = o0 + og * 8 + i;
        const float bias = qkv_b[o];
        const float scale = (o < DK_) ? 0.25f : 1.0f;   // q rows get DKH^-0.5
        float4 v;
        v.x = (acc[i][0] + bias) * scale;
        v.y = (acc[i][1] + bias) * scale;
        v.z = (acc[i][2] + bias) * scale;
        v.w = (acc[i][3] + bias) * scale;
        *(float4*)&qkv[((size_t)b * QKVO_ + o) * HW_ + p0 + pg * 4] = v;
    }
}

// ---------------- K2: attention per (b, head). One lane = one p-row. ----------------
// logits bounded (|l| << 88) -> exp() cannot overflow fp32, skip max-subtraction.
__global__ __launch_bounds__(256) void attn_kernel(
    const float* __restrict__ qkv, float* __restrict__ attn)
{
    const int bx = blockIdx.x;                 // 512 blocks: ((b*8+n)*4 + pc)
    const int pc = bx & 3;
    const int n  = (bx >> 2) & 7;
    const int b  = bx >> 5;
    const int lane = threadIdx.x & 63, wave = threadIdx.x >> 6;
    const int p = pc * 256 + wave * 64 + lane;

    const float* Qb = qkv + ((size_t)b * QKVO_ + n * DKH_) * HW_;
    const float* Kb = qkv + ((size_t)b * QKVO_ + DK_ + n * DKH_) * HW_;
    const float* Vb = qkv + ((size_t)b * QKVO_ + 2 * DK_ + n * DVH_) * HW_;

    float qv[16];
#pragma unroll
    for (int c = 0; c < 16; ++c) qv[c] = Qb[c * HW_ + p];

    float S = 0.f;
    float out[16];
#pragma unroll
    for (int c = 0; c < 16; ++c) out[c] = 0.f;

#pragma unroll 2
    for (int q0 = 0; q0 < HW_; q0 += 4) {
        float l0 = 0.f, l1 = 0.f, l2 = 0.f, l3 = 0.f;
#pragma unroll
        for (int c = 0; c < 16; ++c) {
            const float4 k4 = *(const float4*)(Kb + c * HW_ + q0);  // uniform -> broadcast
            l0 += qv[c] * k4.x; l1 += qv[c] * k4.y;
            l2 += qv[c] * k4.z; l3 += qv[c] * k4.w;
        }
        const float e0 = __expf(l0), e1 = __expf(l1), e2 = __expf(l2), e3 = __expf(l3);
        S += (e0 + e1) + (e2 + e3);
#pragma unroll
        for (int c = 0; c < 16; ++c) {
            const float4 v4 = *(const float4*)(Vb + c * HW_ + q0);
            out[c] += e0 * v4.x + e1 * v4.y + e2 * v4.z + e3 * v4.w;
        }
    }
    const float inv = 1.0f / S;
#pragma unroll
    for (int c = 0; c < 16; ++c)
        attn[((size_t)b * DV_ + n * DVH_ + c) * HW_ + p] = out[c] * inv;
}

// ---------------- K3: attn output projection W[128,128] * A[128,1024] + bias ----------------
__global__ __launch_bounds__(256) void proj_kernel(
    const float* __restrict__ attn, const float* __restrict__ attn_w,
    const float* __restrict__ attn_b, float* __restrict__ out)
{
    const int pt = blockIdx.x;        // 0..7
    const int b  = blockIdx.y;        // 0..15
    const int tid = threadIdx.x;
    const int og = tid >> 5, pg = tid & 31;
    __shared__ float Ws[128 * 36];
    __shared__ float Xs[32 * 132];

    float acc[16][4];
#pragma unroll
    for (int i = 0; i < 16; ++i)
#pragma unroll
        for (int j = 0; j < 4; ++j) acc[i][j] = 0.f;

    const int p0 = pt * 128;

    for (int k0 = 0; k0 < DV_; k0 += 32) {
        __syncthreads();
        {   // stage W tile: 128 rows x 32 k
            const int r = tid >> 1, c0 = (tid & 1) * 16;
            const float* src = attn_w + (size_t)r * DV_ + k0 + c0;
#pragma unroll
            for (int m = 0; m < 4; ++m)
                *(float4*)&Ws[r * 36 + c0 + m * 4] = *(const float4*)(src + m * 4);
        }
        {   // stage X tile: 32 k x 128 p
            const int kk = tid >> 3, c0 = (tid & 7) * 16;
            const float* src = attn + ((size_t)b * DV_ + k0 + kk) * HW_ + p0 + c0;
#pragma unroll
            for (int m = 0; m < 4; ++m)
                *(float4*)&Xs[kk * 132 + c0 + m * 4] = *(const float4*)(src + m * 4);
        }
        __syncthreads();
#pragma unroll 2
        for (int k = 0; k < 32; ++k) {
            const float4 bb = *(const float4*)&Xs[k * 132 + pg * 4];
#pragma unroll
            for (int i = 0; i < 16; ++i) {
                const float a = Ws[(og * 16 + i) * 36 + k];
                acc[i][0] += a * bb.x;
                acc[i][1] += a * bb.y;
                acc[i][2] += a * bb.z;
                acc[i][3] += a * bb.w;
            }
        }
    }
#pragma unroll
    for (int i = 0; i < 16; ++i) {
        const int o = og * 16 + i;
        const float bias = attn_b[o];
        float4 v;
        v.x = acc[i][0] + bias; v.y = acc[i][1] + bias;
        v.z = acc[i][2] + bias; v.w = acc[i][3] + bias;
        *(float4*)&out[((size_t)b * COUT_ + CCONV_ + o) * HW_ + p0 + pg * 4] = v;
    }
}

// ---------------- K4: 3x3 conv, padding 1 (im2col tile in LDS) ----------------
__global__ __launch_bounds__(256) void conv_kernel(
    const float* __restrict__ x, const float* __restrict__ conv_w,
    const float* __restrict__ conv_b, float* __restrict__ out)
{
    const int strip = blockIdx.x;     // 0..7  (4 output rows each)
    const int cot   = blockIdx.y;     // 0..3  (32 out channels each)
    const int b     = blockIdx.z;     // 0..15
    const int tid = threadIdx.x;
    const int og = tid >> 5, pg = tid & 31;
    __shared__ float Ws[32 * 144];    // 32 co x (16 ci x 9 taps)
    __shared__ float Xs[16 * 204];    // 16 ci x 6 rows x 34 cols

    float acc[4][4];
#pragma unroll
    for (int i = 0; i < 4; ++i)
#pragma unroll
        for (int j = 0; j < 4; ++j) acc[i][j] = 0.f;

    const int r0 = strip * 4;

    for (int ci0 = 0; ci0 < CIN_; ci0 += 16) {
        __syncthreads();
        // stage weights: conv_w[co][ci][kh][kw], 144 contiguous per co row
        for (int idx = tid; idx < 32 * 144; idx += 256) {
            const int cr = idx / 144, rem = idx - cr * 144;
            Ws[idx] = conv_w[(size_t)(cot * 32 + cr) * (CIN_ * 9) + ci0 * 9 + rem];
        }
        // stage input patch with halo (zero-padded)
        for (int idx = tid; idx < 16 * 204; idx += 256) {
            const int ci = idx / 204, rem = idx - ci * 204;
            const int rr = rem / 34, cc = rem - rr * 34;
            const int gr = r0 - 1 + rr, gc = cc - 1;
            float v = 0.f;
            if (gr >= 0 && gr < H_ && gc >= 0 && gc < W_)
                v = x[((size_t)(b * CIN_ + ci0 + ci) * H_ + gr) * W_ + gc];
            Xs[idx] = v;
        }
        __syncthreads();
#pragma unroll 2
        for (int ci = 0; ci < 16; ++ci) {
#pragma unroll
            for (int kw = 0; kw < 3; ++kw) {
                float x6[6];
#pragma unroll
                for (int r = 0; r < 6; ++r) x6[r] = Xs[ci * 204 + r * 34 + pg + kw];
#pragma unroll
                for (int kh = 0; kh < 3; ++kh) {
                    float wv[4];
#pragma unroll
                    for (int i = 0; i < 4; ++i)
                        wv[i] = Ws[(og * 4 + i) * 144 + ci * 9 + kh * 3 + kw];
#pragma unroll
                    for (int i = 0; i < 4; ++i)
#pragma unroll
                        for (int j = 0; j < 4; ++j)
                            acc[i][j] += wv[i] * x6[kh + j];
                }
            }
        }
    }
#pragma unroll
    for (int i = 0; i < 4; ++i) {
        const int co = cot * 32 + og * 4 + i;
        const float bias = conv_b[co];
#pragma unroll
        for (int j = 0; j < 4; ++j)
            out[((size_t)(b * COUT_ + co) * H_ + r0 + j) * W_ + pg] = acc[i][j] + bias;
    }
}

extern "C" void kernel_launch(void* const* d_in, const int* in_sizes, int n_in,
                              void* d_out, int out_size, void* d_ws, size_t ws_size,
                              hipStream_t stream)
{
    (void)in_sizes; (void)n_in; (void)out_size; (void)ws_size;
    const float* x      = (const float*)d_in[0];
    const float* conv_w = (const float*)d_in[1];
    const float* conv_b = (const float*)d_in[2];
    const float* qkv_w  = (const float*)d_in[3];
    const float* qkv_b  = (const float*)d_in[4];
    const float* attn_w = (const float*)d_in[5];
    const float* attn_b = (const float*)d_in[6];
    float* out = (float*)d_out;

    float* qkv  = (float*)d_ws;                       // [B][384][1024]  25 MB
    float* attn = qkv + (size_t)B_ * QKVO_ * HW_;     // [B][128][1024]   8 MB

    qkv_kernel<<<dim3(8, 6, B_), dim3(256), 0, stream>>>(x, qkv_w, qkv_b, qkv);
    attn_kernel<<<dim3(512), dim3(256), 0, stream>>>(qkv, attn);
    proj_kernel<<<dim3(8, B_), dim3(256), 0, stream>>>(attn, attn_w, attn_b, out);
    conv_kernel<<<dim3(8, 4, B_), dim3(256), 0, stream>>>(x, conv_w, conv_b, out);
}

// Round 3
// 388.543 us; speedup vs baseline: 1.9045x; 1.9045x over previous
//
#include <hip/hip_runtime.h>
#include <cstddef>

#define B_ 16
#define CIN_ 256
#define H_ 32
#define W_ 32
#define HW_ 1024
#define COUT_ 256
#define DK_ 128
#define DV_ 128
#define NH_ 8
#define DKH_ 16
#define DVH_ 16
#define CCONV_ 128
#define QKVO_ 384

typedef __attribute__((ext_vector_type(4))) _Float16 half4v;
typedef __attribute__((ext_vector_type(4))) float float4v;

// ---------------- K1: qkv 1x1 conv == GEMM W[384,256] * X[256,1024] per image ----------------
__global__ __launch_bounds__(256) void qkv_kernel(
    const float* __restrict__ x, const float* __restrict__ qkv_w,
    const float* __restrict__ qkv_b, float* __restrict__ qkv)
{
    const int pt = blockIdx.x;        // 0..7   (128 pixels)
    const int ot = blockIdx.y;        // 0..5   (64 outputs)
    const int b  = blockIdx.z;        // 0..15
    const int tid = threadIdx.x;
    const int og = tid >> 5;          // 0..7
    const int pg = tid & 31;          // 0..31
    __shared__ float Ws[64 * 36];
    __shared__ float Xs[32 * 132];

    float acc[8][4];
#pragma unroll
    for (int i = 0; i < 8; ++i)
#pragma unroll
        for (int j = 0; j < 4; ++j) acc[i][j] = 0.f;

    const int o0 = ot * 64, p0 = pt * 128;

    for (int k0 = 0; k0 < CIN_; k0 += 32) {
        __syncthreads();
        {   // stage W tile: 64 rows x 32 k
            const int r = tid >> 2, c0 = (tid & 3) * 8;
            const float* src = qkv_w + (size_t)(o0 + r) * CIN_ + k0 + c0;
            *(float4*)&Ws[r * 36 + c0]     = *(const float4*)src;
            *(float4*)&Ws[r * 36 + c0 + 4] = *(const float4*)(src + 4);
        }
        {   // stage X tile: 32 k x 128 p
            const int kk = tid >> 3, c0 = (tid & 7) * 16;
            const float* src = x + ((size_t)b * CIN_ + k0 + kk) * HW_ + p0 + c0;
#pragma unroll
            for (int m = 0; m < 4; ++m)
                *(float4*)&Xs[kk * 132 + c0 + m * 4] = *(const float4*)(src + m * 4);
        }
        __syncthreads();
#pragma unroll 4
        for (int k = 0; k < 32; ++k) {
            float a[8];
#pragma unroll
            for (int i = 0; i < 8; ++i) a[i] = Ws[(og * 8 + i) * 36 + k];
            const float4 bb = *(const float4*)&Xs[k * 132 + pg * 4];
#pragma unroll
            for (int i = 0; i < 8; ++i) {
                acc[i][0] += a[i] * bb.x;
                acc[i][1] += a[i] * bb.y;
                acc[i][2] += a[i] * bb.z;
                acc[i][3] += a[i] * bb.w;
            }
        }
    }
#pragma unroll
    for (int i = 0; i < 8; ++i) {
        const int o = o0 + og * 8 + i;
        const float bias = qkv_b[o];
        const float scale = (o < DK_) ? 0.25f : 1.0f;   // q rows get DKH^-0.5
        float4 v;
        v.x = (acc[i][0] + bias) * scale;
        v.y = (acc[i][1] + bias) * scale;
        v.z = (acc[i][2] + bias) * scale;
        v.w = (acc[i][3] + bias) * scale;
        *(float4*)&qkv[((size_t)b * QKVO_ + o) * HW_ + p0 + pg * 4] = v;
    }
}

// ---------------- K2: repack fp32 qkv -> f16 fragment-friendly layouts ----------------
// which=0: Q -> Qt[b][n][p][c]   (pixel-major, 16 ch)
// which=1: K -> Kt[b][n][p][c]
// which=2: V -> Vt[b][n][c][q]   (channel-major, straight convert)
__global__ __launch_bounds__(256) void repack_kernel(
    const float* __restrict__ qkv, _Float16* __restrict__ Qt,
    _Float16* __restrict__ Kt, _Float16* __restrict__ Vt)
{
    const int tile = blockIdx.x;          // 0..15
    const int n    = blockIdx.y;          // 0..7
    const int zz   = blockIdx.z;          // b*3 + which
    const int which = zz % 3, b = zz / 3;
    const int t = threadIdx.x;
    const size_t head = (size_t)(b * NH_ + n) * (HW_ * 16);

    if (which == 2) {
        const int i0 = tile * 1024 + t * 4;
        const float4 v = *(const float4*)(qkv + ((size_t)b * QKVO_ + 2 * DK_ + n * 16) * HW_ + i0);
        half4v h; h[0] = (_Float16)v.x; h[1] = (_Float16)v.y; h[2] = (_Float16)v.z; h[3] = (_Float16)v.w;
        *(half4v*)(Vt + head + i0) = h;
    } else {
        const int p  = tile * 64 + (t >> 2);
        const int c0 = (t & 3) * 4;
        const int chbase = (which == 0 ? 0 : DK_) + n * 16;
        const float* src = qkv + ((size_t)b * QKVO_ + chbase + c0) * HW_ + p;
        half4v h;
#pragma unroll
        for (int i = 0; i < 4; ++i) h[i] = (_Float16)src[i * HW_];
        _Float16* dst = (which == 0 ? Qt : Kt) + head + (size_t)p * 16 + c0;
        *(half4v*)dst = h;
    }
}

// ---------------- K3: fused MFMA attention, swapped-operand trick ----------------
// Per (b, n): S2[q,p] = sum_c K[q,c] Q[c,p] via mfma(A=K, B=Q).
// exp in regs; C-layout of S2 == B-layout needed for O^T[c,p] += mfma(A=V, B=P).
// Logits are O(1) -> no max subtraction needed; denom via shfl reduce.
__global__ __launch_bounds__(256) void attn_kernel(
    const _Float16* __restrict__ Qt, const _Float16* __restrict__ Kt,
    const _Float16* __restrict__ Vt, float* __restrict__ attn)
{
    const int bx = blockIdx.x;                 // ((b*8+n)*4 + pc)
    const int pc = bx & 3;
    const int n  = (bx >> 2) & 7;
    const int b  = bx >> 5;
    const int lane = threadIdx.x & 63, wave = threadIdx.x >> 6;
    const int l16 = lane & 15, lg = lane >> 4;

    const size_t head = (size_t)(b * NH_ + n) * (HW_ * 16);
    const _Float16* Qh = Qt + head;
    const _Float16* Kh = Kt + head;
    const _Float16* Vh = Vt + head;            // [16][1024]

    const int pbase = pc * 256 + wave * 64;

    half4v qf[4];
#pragma unroll
    for (int t = 0; t < 4; ++t)
        qf[t] = *(const half4v*)(Qh + (size_t)(pbase + t * 16 + l16) * 16 + lg * 4);

    float4v o[4];
    float rs[4];
#pragma unroll
    for (int t = 0; t < 4; ++t) { o[t] = (float4v){0.f, 0.f, 0.f, 0.f}; rs[t] = 0.f; }

    const float4v zero = (float4v){0.f, 0.f, 0.f, 0.f};

    for (int q0 = 0; q0 < HW_; q0 += 16) {
        const half4v kf = *(const half4v*)(Kh + (size_t)(q0 + l16) * 16 + lg * 4);
        const half4v vf = *(const half4v*)(Vh + (size_t)l16 * HW_ + q0 + lg * 4);
#pragma unroll
        for (int t = 0; t < 4; ++t) {
            float4v s = __builtin_amdgcn_mfma_f32_16x16x16f16(kf, qf[t], zero, 0, 0, 0);
            const float e0 = __expf(s[0]);
            const float e1 = __expf(s[1]);
            const float e2 = __expf(s[2]);
            const float e3 = __expf(s[3]);
            rs[t] += (e0 + e1) + (e2 + e3);
            half4v pf;
            pf[0] = (_Float16)e0; pf[1] = (_Float16)e1;
            pf[2] = (_Float16)e2; pf[3] = (_Float16)e3;
            o[t] = __builtin_amdgcn_mfma_f32_16x16x16f16(vf, pf, o[t], 0, 0, 0);
        }
    }
#pragma unroll
    for (int t = 0; t < 4; ++t) {
        float r = rs[t];
        r += __shfl_xor(r, 16);
        r += __shfl_xor(r, 32);
        const float inv = 1.0f / r;
        const int p = pbase + t * 16 + l16;
#pragma unroll
        for (int rr = 0; rr < 4; ++rr)
            attn[((size_t)b * DV_ + n * 16 + lg * 4 + rr) * HW_ + p] = o[t][rr] * inv;
    }
}

// ---------------- K4: attn output projection W[128,128] * A[128,1024] + bias ----------------
__global__ __launch_bounds__(256) void proj_kernel(
    const float* __restrict__ attn, const float* __restrict__ attn_w,
    const float* __restrict__ attn_b, float* __restrict__ out)
{
    const int pt = blockIdx.x;        // 0..7
    const int b  = blockIdx.y;        // 0..15
    const int tid = threadIdx.x;
    const int og = tid >> 5, pg = tid & 31;
    __shared__ float Ws[128 * 36];
    __shared__ float Xs[32 * 132];

    float acc[16][4];
#pragma unroll
    for (int i = 0; i < 16; ++i)
#pragma unroll
        for (int j = 0; j < 4; ++j) acc[i][j] = 0.f;

    const int p0 = pt * 128;

    for (int k0 = 0; k0 < DV_; k0 += 32) {
        __syncthreads();
        {   // stage W tile: 128 rows x 32 k
            const int r = tid >> 1, c0 = (tid & 1) * 16;
            const float* src = attn_w + (size_t)r * DV_ + k0 + c0;
#pragma unroll
            for (int m = 0; m < 4; ++m)
                *(float4*)&Ws[r * 36 + c0 + m * 4] = *(const float4*)(src + m * 4);
        }
        {   // stage X tile: 32 k x 128 p
            const int kk = tid >> 3, c0 = (tid & 7) * 16;
            const float* src = attn + ((size_t)b * DV_ + k0 + kk) * HW_ + p0 + c0;
#pragma unroll
            for (int m = 0; m < 4; ++m)
                *(float4*)&Xs[kk * 132 + c0 + m * 4] = *(const float4*)(src + m * 4);
        }
        __syncthreads();
#pragma unroll 2
        for (int k = 0; k < 32; ++k) {
            const float4 bb = *(const float4*)&Xs[k * 132 + pg * 4];
#pragma unroll
            for (int i = 0; i < 16; ++i) {
                const float a = Ws[(og * 16 + i) * 36 + k];
                acc[i][0] += a * bb.x;
                acc[i][1] += a * bb.y;
                acc[i][2] += a * bb.z;
                acc[i][3] += a * bb.w;
            }
        }
    }
#pragma unroll
    for (int i = 0; i < 16; ++i) {
        const int o = og * 16 + i;
        const float bias = attn_b[o];
        float4 v;
        v.x = acc[i][0] + bias; v.y = acc[i][1] + bias;
        v.z = acc[i][2] + bias; v.w = acc[i][3] + bias;
        *(float4*)&out[((size_t)b * COUT_ + CCONV_ + o) * HW_ + p0 + pg * 4] = v;
    }
}

// ---------------- K5: 3x3 conv, padding 1 (im2col tile in LDS) ----------------
__global__ __launch_bounds__(256) void conv_kernel(
    const float* __restrict__ x, const float* __restrict__ conv_w,
    const float* __restrict__ conv_b, float* __restrict__ out)
{
    const int strip = blockIdx.x;     // 0..7  (4 output rows each)
    const int cot   = blockIdx.y;     // 0..3  (32 out channels each)
    const int b     = blockIdx.z;     // 0..15
    const int tid = threadIdx.x;
    const int og = tid >> 5, pg = tid & 31;
    __shared__ float Ws[32 * 144];    // 32 co x (16 ci x 9 taps)
    __shared__ float Xs[16 * 204];    // 16 ci x 6 rows x 34 cols

    float acc[4][4];
#pragma unroll
    for (int i = 0; i < 4; ++i)
#pragma unroll
        for (int j = 0; j < 4; ++j) acc[i][j] = 0.f;

    const int r0 = strip * 4;

    for (int ci0 = 0; ci0 < CIN_; ci0 += 16) {
        __syncthreads();
        for (int idx = tid; idx < 32 * 144; idx += 256) {
            const int cr = idx / 144, rem = idx - cr * 144;
            Ws[idx] = conv_w[(size_t)(cot * 32 + cr) * (CIN_ * 9) + ci0 * 9 + rem];
        }
        for (int idx = tid; idx < 16 * 204; idx += 256) {
            const int ci = idx / 204, rem = idx - ci * 204;
            const int rr = rem / 34, cc = rem - rr * 34;
            const int gr = r0 - 1 + rr, gc = cc - 1;
            float v = 0.f;
            if (gr >= 0 && gr < H_ && gc >= 0 && gc < W_)
                v = x[((size_t)(b * CIN_ + ci0 + ci) * H_ + gr) * W_ + gc];
            Xs[idx] = v;
        }
        __syncthreads();
#pragma unroll 2
        for (int ci = 0; ci < 16; ++ci) {
#pragma unroll
            for (int kw = 0; kw < 3; ++kw) {
                float x6[6];
#pragma unroll
                for (int r = 0; r < 6; ++r) x6[r] = Xs[ci * 204 + r * 34 + pg + kw];
#pragma unroll
                for (int kh = 0; kh < 3; ++kh) {
                    float wv[4];
#pragma unroll
                    for (int i = 0; i < 4; ++i)
                        wv[i] = Ws[(og * 4 + i) * 144 + ci * 9 + kh * 3 + kw];
#pragma unroll
                    for (int i = 0; i < 4; ++i)
#pragma unroll
                        for (int j = 0; j < 4; ++j)
                            acc[i][j] += wv[i] * x6[kh + j];
                }
            }
        }
    }
#pragma unroll
    for (int i = 0; i < 4; ++i) {
        const int co = cot * 32 + og * 4 + i;
        const float bias = conv_b[co];
#pragma unroll
        for (int j = 0; j < 4; ++j)
            out[((size_t)(b * COUT_ + co) * H_ + r0 + j) * W_ + pg] = acc[i][j] + bias;
    }
}

extern "C" void kernel_launch(void* const* d_in, const int* in_sizes, int n_in,
                              void* d_out, int out_size, void* d_ws, size_t ws_size,
                              hipStream_t stream)
{
    (void)in_sizes; (void)n_in; (void)out_size; (void)ws_size;
    const float* x      = (const float*)d_in[0];
    const float* conv_w = (const float*)d_in[1];
    const float* conv_b = (const float*)d_in[2];
    const float* qkv_w  = (const float*)d_in[3];
    const float* qkv_b  = (const float*)d_in[4];
    const float* attn_w = (const float*)d_in[5];
    const float* attn_b = (const float*)d_in[6];
    float* out = (float*)d_out;

    float* qkvf = (float*)d_ws;                               // [16][384][1024] fp32, 25 MB
    _Float16* Qt = (_Float16*)((char*)d_ws + (size_t)B_ * QKVO_ * HW_ * 4);
    _Float16* Kt = Qt + (size_t)B_ * NH_ * HW_ * 16;          // 4 MB each
    _Float16* Vt = Kt + (size_t)B_ * NH_ * HW_ * 16;
    float* attnf = qkvf;   // alias: fp32 qkv is dead once repack has run

    qkv_kernel<<<dim3(8, 6, B_), dim3(256), 0, stream>>>(x, qkv_w, qkv_b, qkvf);
    repack_kernel<<<dim3(16, NH_, B_ * 3), dim3(256), 0, stream>>>(qkvf, Qt, Kt, Vt);
    attn_kernel<<<dim3(512), dim3(256), 0, stream>>>(Qt, Kt, Vt, attnf);
    proj_kernel<<<dim3(8, B_), dim3(256), 0, stream>>>(attnf, attn_w, attn_b, out);
    conv_kernel<<<dim3(8, 4, B_), dim3(256), 0, stream>>>(x, conv_w, conv_b, out);
}

// Round 5
// 233.692 us; speedup vs baseline: 3.1665x; 1.6626x over previous
//
#include <hip/hip_runtime.h>
#include <cstddef>

#define B_ 16
#define CIN_ 256
#define H_ 32
#define W_ 32
#define HW_ 1024
#define COUT_ 256
#define DK_ 128
#define DV_ 128
#define NH_ 8
#define DKH_ 16
#define DVH_ 16
#define CCONV_ 128
#define QKVO_ 384

typedef __attribute__((ext_vector_type(4))) _Float16 half4v;
typedef __attribute__((ext_vector_type(4))) float float4v;

// ---------------- K0: transpose+convert x -> xT16[b][pix][ci] ----------------
__global__ __launch_bounds__(256) void xt_kernel(
    const float* __restrict__ x, _Float16* __restrict__ xT)
{
    const int pt = blockIdx.x;   // 0..31 pixel tile
    const int ct = blockIdx.y;   // 0..7  ci tile
    const int b  = blockIdx.z;
    __shared__ float T[32][33];
    const int t = threadIdx.x;
    const int c = t & 31, r = t >> 5;
#pragma unroll
    for (int i = 0; i < 4; ++i) {
        const int ci = ct * 32 + r + i * 8;
        T[r + i * 8][c] = x[(size_t)(b * CIN_ + ci) * HW_ + pt * 32 + c];
    }
    __syncthreads();
    // one half4v per thread: 32 pix x 8 ci-quads = 256
    const int cq = (t & 7) * 4;
    const int pi = t >> 3;
    half4v h;
#pragma unroll
    for (int j = 0; j < 4; ++j) h[j] = (_Float16)T[cq + j][pi];
    *(half4v*)(xT + (size_t)(b * HW_ + pt * 32 + pi) * CIN_ + ct * 32 + cq) = h;
}

// ---------------- K0b: conv_w[co][ci][tap] -> w16c[tap][co][ci] (f16) ----------------
__global__ __launch_bounds__(256) void wc_kernel(
    const float* __restrict__ conv_w, _Float16* __restrict__ w16c)
{
    const int id = blockIdx.x * 256 + threadIdx.x;   // co*256+ci, 0..32767
    const int co = id >> 8, ci = id & 255;
    const float* src = conv_w + (size_t)id * 9;
#pragma unroll
    for (int j = 0; j < 9; ++j)
        w16c[(size_t)(j * CCONV_ + co) * CIN_ + ci] = (_Float16)src[j];
}

// ---------------- K0c: qkv_w -> f16 ----------------
__global__ __launch_bounds__(256) void wq_kernel(
    const float* __restrict__ qkv_w, _Float16* __restrict__ w16q)
{
    const int i = (blockIdx.x * 256 + threadIdx.x) * 4;   // < 98304
    const float4 v = *(const float4*)(qkv_w + i);
    half4v h; h[0] = (_Float16)v.x; h[1] = (_Float16)v.y;
    h[2] = (_Float16)v.z; h[3] = (_Float16)v.w;
    *(half4v*)(w16q + i) = h;
}

// ---------------- K1: qkv MFMA GEMM, writes Qt/Kt/Vt directly ----------------
// A = w16q[o][k] (row=l&15), B = xT[p][k] (col=l&15), both 8B frag loads, no LDS.
__global__ __launch_bounds__(256) void qkv_kernel(
    const _Float16* __restrict__ xT, const _Float16* __restrict__ w16q,
    const float* __restrict__ qkv_b, _Float16* __restrict__ Qt,
    _Float16* __restrict__ Kt, _Float16* __restrict__ Vt)
{
    const int pt = blockIdx.x;   // 0..7  (128 pixels)
    const int ot = blockIdx.y;   // 0..5  (64 outputs)
    const int b  = blockIdx.z;
    const int lane = threadIdx.x & 63, w = threadIdx.x >> 6;
    const int l16 = lane & 15, hi = lane >> 4;
    const int p0 = pt * 128;

    const _Float16* Arow = w16q + (size_t)(ot * 64 + w * 16 + l16) * CIN_ + hi * 4;
    const _Float16* Brow = xT + (size_t)(b * HW_ + p0 + l16) * CIN_ + hi * 4;

    float4v acc[8];
#pragma unroll
    for (int pg = 0; pg < 8; ++pg) acc[pg] = (float4v){0.f, 0.f, 0.f, 0.f};

    for (int k0 = 0; k0 < CIN_; k0 += 16) {
        const half4v a = *(const half4v*)(Arow + k0);
#pragma unroll
        for (int pg = 0; pg < 8; ++pg) {
            const half4v bf = *(const half4v*)(Brow + (size_t)pg * 16 * CIN_ + k0);
            acc[pg] = __builtin_amdgcn_mfma_f32_16x16x16f16(a, bf, acc[pg], 0, 0, 0);
        }
    }

    const int og = ot * 4 + w;          // 0..23: 0-7 Q heads, 8-15 K, 16-23 V
    float bias[4];
#pragma unroll
    for (int r = 0; r < 4; ++r) bias[r] = qkv_b[ot * 64 + w * 16 + hi * 4 + r];

    if (og < 16) {
        const float scale = (og < 8) ? 0.25f : 1.0f;    // DKH^-0.5
        _Float16* dst = (og < 8 ? Qt : Kt) + (size_t)(b * NH_ + (og & 7)) * (HW_ * 16) + hi * 4;
#pragma unroll
        for (int pg = 0; pg < 8; ++pg) {
            const int p = p0 + pg * 16 + l16;
            half4v h;
#pragma unroll
            for (int r = 0; r < 4; ++r) h[r] = (_Float16)((acc[pg][r] + bias[r]) * scale);
            *(half4v*)(dst + (size_t)p * 16) = h;
        }
    } else {
        _Float16* Vb = Vt + (size_t)(b * NH_ + (og - 16)) * (16 * HW_);
#pragma unroll
        for (int pg = 0; pg < 8; ++pg) {
            const int p = p0 + pg * 16 + l16;
#pragma unroll
            for (int r = 0; r < 4; ++r)
                Vb[(size_t)(hi * 4 + r) * HW_ + p] = (_Float16)(acc[pg][r] + bias[r]);
        }
    }
}

// ---------------- K2: fused MFMA attention (unchanged, verified R3) ----------------
__global__ __launch_bounds__(256) void attn_kernel(
    const _Float16* __restrict__ Qt, const _Float16* __restrict__ Kt,
    const _Float16* __restrict__ Vt, float* __restrict__ attn)
{
    const int bx = blockIdx.x;                 // ((b*8+n)*4 + pc)
    const int pc = bx & 3;
    const int n  = (bx >> 2) & 7;
    const int b  = bx >> 5;
    const int lane = threadIdx.x & 63, wave = threadIdx.x >> 6;
    const int l16 = lane & 15, lg = lane >> 4;

    const size_t head = (size_t)(b * NH_ + n) * (HW_ * 16);
    const _Float16* Qh = Qt + head;
    const _Float16* Kh = Kt + head;
    const _Float16* Vh = Vt + head;            // [16][1024]

    const int pbase = pc * 256 + wave * 64;

    half4v qf[4];
#pragma unroll
    for (int t = 0; t < 4; ++t)
        qf[t] = *(const half4v*)(Qh + (size_t)(pbase + t * 16 + l16) * 16 + lg * 4);

    float4v o[4];
    float rs[4];
#pragma unroll
    for (int t = 0; t < 4; ++t) { o[t] = (float4v){0.f, 0.f, 0.f, 0.f}; rs[t] = 0.f; }

    const float4v zero = (float4v){0.f, 0.f, 0.f, 0.f};

    for (int q0 = 0; q0 < HW_; q0 += 16) {
        const half4v kf = *(const half4v*)(Kh + (size_t)(q0 + l16) * 16 + lg * 4);
        const half4v vf = *(const half4v*)(Vh + (size_t)l16 * HW_ + q0 + lg * 4);
#pragma unroll
        for (int t = 0; t < 4; ++t) {
            float4v s = __builtin_amdgcn_mfma_f32_16x16x16f16(kf, qf[t], zero, 0, 0, 0);
            const float e0 = __expf(s[0]);
            const float e1 = __expf(s[1]);
            const float e2 = __expf(s[2]);
            const float e3 = __expf(s[3]);
            rs[t] += (e0 + e1) + (e2 + e3);
            half4v pf;
            pf[0] = (_Float16)e0; pf[1] = (_Float16)e1;
            pf[2] = (_Float16)e2; pf[3] = (_Float16)e3;
            o[t] = __builtin_amdgcn_mfma_f32_16x16x16f16(vf, pf, o[t], 0, 0, 0);
        }
    }
#pragma unroll
    for (int t = 0; t < 4; ++t) {
        float r = rs[t];
        r += __shfl_xor(r, 16);
        r += __shfl_xor(r, 32);
        const float inv = 1.0f / r;
        const int p = pbase + t * 16 + l16;
#pragma unroll
        for (int rr = 0; rr < 4; ++rr)
            attn[((size_t)b * DV_ + n * 16 + lg * 4 + rr) * HW_ + p] = o[t][rr] * inv;
    }
}

// ---------------- K3: attn output projection (fp32 VALU, small) ----------------
__global__ __launch_bounds__(256) void proj_kernel(
    const float* __restrict__ attn, const float* __restrict__ attn_w,
    const float* __restrict__ attn_b, float* __restrict__ out)
{
    const int pt = blockIdx.x;        // 0..7
    const int b  = blockIdx.y;        // 0..15
    const int tid = threadIdx.x;
    const int og = tid >> 5, pg = tid & 31;
    __shared__ float Ws[128 * 36];
    __shared__ float Xs[32 * 132];

    float acc[16][4];
#pragma unroll
    for (int i = 0; i < 16; ++i)
#pragma unroll
        for (int j = 0; j < 4; ++j) acc[i][j] = 0.f;

    const int p0 = pt * 128;

    for (int k0 = 0; k0 < DV_; k0 += 32) {
        __syncthreads();
        {
            const int r = tid >> 1, c0 = (tid & 1) * 16;
            const float* src = attn_w + (size_t)r * DV_ + k0 + c0;
#pragma unroll
            for (int m = 0; m < 4; ++m)
                *(float4*)&Ws[r * 36 + c0 + m * 4] = *(const float4*)(src + m * 4);
        }
        {
            const int kk = tid >> 3, c0 = (tid & 7) * 16;
            const float* src = attn + ((size_t)b * DV_ + k0 + kk) * HW_ + p0 + c0;
#pragma unroll
            for (int m = 0; m < 4; ++m)
                *(float4*)&Xs[kk * 132 + c0 + m * 4] = *(const float4*)(src + m * 4);
        }
        __syncthreads();
#pragma unroll 2
        for (int k = 0; k < 32; ++k) {
            const float4 bb = *(const float4*)&Xs[k * 132 + pg * 4];
#pragma unroll
            for (int i = 0; i < 16; ++i) {
                const float a = Ws[(og * 16 + i) * 36 + k];
                acc[i][0] += a * bb.x;
                acc[i][1] += a * bb.y;
                acc[i][2] += a * bb.z;
                acc[i][3] += a * bb.w;
            }
        }
    }
#pragma unroll
    for (int i = 0; i < 16; ++i) {
        const int o = og * 16 + i;
        const float bias = attn_b[o];
        float4 v;
        v.x = acc[i][0] + bias; v.y = acc[i][1] + bias;
        v.z = acc[i][2] + bias; v.w = acc[i][3] + bias;
        *(float4*)&out[((size_t)b * COUT_ + CCONV_ + o) * HW_ + p0 + pg * 4] = v;
    }
}

// ---------------- K4: 3x3 conv as implicit-GEMM MFMA ----------------
// Block: 32 co x (4 rows x 32 cols). Wave w owns output row r0+w.
// LDS: W[9 taps][32 co][16 ci], X halo [6 rows][34 cols][16 ci] (f16, ci contig).
__global__ __launch_bounds__(256) void conv_kernel(
    const _Float16* __restrict__ xT, const _Float16* __restrict__ w16c,
    const float* __restrict__ conv_b, float* __restrict__ out)
{
    const int strip = blockIdx.x;  // 0..7
    const int cot   = blockIdx.y;  // 0..3
    const int b     = blockIdx.z;
    const int t = threadIdx.x;
    const int lane = t & 63, w = t >> 6;
    const int l16 = lane & 15, hi = lane >> 4;
    const int r0 = strip * 4, co0 = cot * 32;

    __shared__ _Float16 Wl[9 * 32 * 16];    // 9216 B
    __shared__ _Float16 Xs[204 * 16];       // 6528 B

    float4v acc[2][2];
#pragma unroll
    for (int i = 0; i < 2; ++i)
#pragma unroll
        for (int j = 0; j < 2; ++j) acc[i][j] = (float4v){0.f, 0.f, 0.f, 0.f};

    for (int ci0 = 0; ci0 < CIN_; ci0 += 16) {
        __syncthreads();
        // stage W: 288 rows of 32 B
        for (int i = t; i < 288; i += 256) {
            const int tap = i >> 5, co = i & 31;
            const uint4* s = (const uint4*)(w16c + (size_t)(tap * CCONV_ + co0 + co) * CIN_ + ci0);
            uint4* d = (uint4*)(Wl + i * 16);
            d[0] = s[0]; d[1] = s[1];
        }
        // stage X halo: 204 pixels of 32 B, zero-padded
        for (int i = t; i < 204; i += 256) {
            const int hr = i / 34, hc = i - hr * 34;
            const int gr = r0 - 1 + hr, gc = hc - 1;
            uint4* d = (uint4*)(Xs + i * 16);
            if (gr >= 0 && gr < H_ && gc >= 0 && gc < W_) {
                const uint4* s = (const uint4*)(xT + (size_t)(b * HW_ + gr * 32 + gc) * CIN_ + ci0);
                d[0] = s[0]; d[1] = s[1];
            } else {
                uint4 z; z.x = z.y = z.z = z.w = 0u;
                d[0] = z; d[1] = z;
            }
        }
        __syncthreads();
#pragma unroll
        for (int kh = 0; kh < 3; ++kh) {
#pragma unroll
            for (int kw = 0; kw < 3; ++kw) {
                const int tap = kh * 3 + kw;
                const half4v a0 = *(const half4v*)(Wl + (tap * 32 + l16) * 16 + hi * 4);
                const half4v a1 = *(const half4v*)(Wl + (tap * 32 + 16 + l16) * 16 + hi * 4);
                const half4v b0 = *(const half4v*)(Xs + ((w + kh) * 34 + l16 + kw) * 16 + hi * 4);
                const half4v b1 = *(const half4v*)(Xs + ((w + kh) * 34 + 16 + l16 + kw) * 16 + hi * 4);
                acc[0][0] = __builtin_amdgcn_mfma_f32_16x16x16f16(a0, b0, acc[0][0], 0, 0, 0);
                acc[0][1] = __builtin_amdgcn_mfma_f32_16x16x16f16(a0, b1, acc[0][1], 0, 0, 0);
                acc[1][0] = __builtin_amdgcn_mfma_f32_16x16x16f16(a1, b0, acc[1][0], 0, 0, 0);
                acc[1][1] = __builtin_amdgcn_mfma_f32_16x16x16f16(a1, b1, acc[1][1], 0, 0, 0);
            }
        }
    }
    const int row = r0 + w;
#pragma unroll
    for (int cog = 0; cog < 2; ++cog)
#pragma unroll
        for (int r = 0; r < 4; ++r) {
            const int co = co0 + cog * 16 + hi * 4 + r;
            const float bias = conv_b[co];
            float* dst = out + (size_t)(b * COUT_ + co) * HW_ + row * 32;
            dst[l16]      = acc[cog][0][r] + bias;
            dst[16 + l16] = acc[cog][1][r] + bias;
        }
}

extern "C" void kernel_launch(void* const* d_in, const int* in_sizes, int n_in,
                              void* d_out, int out_size, void* d_ws, size_t ws_size,
                              hipStream_t stream)
{
    (void)in_sizes; (void)n_in; (void)out_size; (void)ws_size;
    const float* x      = (const float*)d_in[0];
    const float* conv_w = (const float*)d_in[1];
    const float* conv_b = (const float*)d_in[2];
    const float* qkv_w  = (const float*)d_in[3];
    const float* qkv_b  = (const float*)d_in[4];
    const float* attn_w = (const float*)d_in[5];
    const float* attn_b = (const float*)d_in[6];
    float* out = (float*)d_out;

    char* ws = (char*)d_ws;
    _Float16* xT   = (_Float16*)(ws);               // 16*1024*256*2 = 8388608
    _Float16* w16c = (_Float16*)(ws + 8388608);     // 9*128*256*2   = 589824
    _Float16* w16q = (_Float16*)(ws + 8978432);     // 384*256*2     = 196608
    _Float16* Qt   = (_Float16*)(ws + 9175040);     // 16*8*1024*16*2 = 4194304
    _Float16* Kt   = (_Float16*)(ws + 13369344);
    _Float16* Vt   = (_Float16*)(ws + 17563648);
    float*    attnf = (float*)   (ws + 21757952);   // 16*128*1024*4 = 8388608

    xt_kernel<<<dim3(32, 8, B_), dim3(256), 0, stream>>>(x, xT);
    wc_kernel<<<dim3(128), dim3(256), 0, stream>>>(conv_w, w16c);
    wq_kernel<<<dim3(96), dim3(256), 0, stream>>>(qkv_w, w16q);
    qkv_kernel<<<dim3(8, 6, B_), dim3(256), 0, stream>>>(xT, w16q, qkv_b, Qt, Kt, Vt);
    attn_kernel<<<dim3(512), dim3(256), 0, stream>>>(Qt, Kt, Vt, attnf);
    proj_kernel<<<dim3(8, B_), dim3(256), 0, stream>>>(attnf, attn_w, attn_b, out);
    conv_kernel<<<dim3(8, 4, B_), dim3(256), 0, stream>>>(xT, w16c, conv_b, out);
}

// Round 7
// 187.813 us; speedup vs baseline: 3.9401x; 1.2443x over previous
//
#include <hip/hip_runtime.h>
#include <cstddef>

#define B_ 16
#define CIN_ 256
#define H_ 32
#define W_ 32
#define HW_ 1024
#define COUT_ 256
#define DK_ 128
#define DV_ 128
#define NH_ 8
#define DKH_ 16
#define DVH_ 16
#define CCONV_ 128
#define QKVO_ 384

typedef __attribute__((ext_vector_type(4))) _Float16 half4v;
typedef __attribute__((ext_vector_type(4))) float float4v;

// Fragment-major convention for mfma_f32_16x16x16f16 operands:
//   store M[chunk kc][row-or-col r (16)][k16 (16)] contiguously;
//   lane (l16=r, hi=k>>2) loads 8 B at ((kc*NR + r0+l16)*16 + hi*4)
//   -> the wave's 64 lanes cover one contiguous 512-B block.

// ---------------- K0: x -> xT[b][pix][ci] (for conv) + xF[b][kc][pix][k16] (for qkv) ----------------
__global__ __launch_bounds__(256) void xt_kernel(
    const float* __restrict__ x, _Float16* __restrict__ xT, _Float16* __restrict__ xF)
{
    const int pt = blockIdx.x;   // 0..31 pixel tile
    const int ct = blockIdx.y;   // 0..7  ci tile
    const int b  = blockIdx.z;
    __shared__ float T[32][33];
    const int t = threadIdx.x;
    const int c = t & 31, r = t >> 5;
#pragma unroll
    for (int i = 0; i < 4; ++i) {
        const int ci = ct * 32 + r + i * 8;
        T[r + i * 8][c] = x[(size_t)(b * CIN_ + ci) * HW_ + pt * 32 + c];
    }
    __syncthreads();
    // one half4v per thread: 32 pix x 8 ci-quads = 256
    const int cq = (t & 7) * 4;
    const int pi = t >> 3;
    half4v h;
#pragma unroll
    for (int j = 0; j < 4; ++j) h[j] = (_Float16)T[cq + j][pi];
    const int p = pt * 32 + pi;
    *(half4v*)(xT + (size_t)(b * HW_ + p) * CIN_ + ct * 32 + cq) = h;
    const int kc = ct * 2 + (cq >> 4), k16 = cq & 15;
    *(half4v*)(xF + ((size_t)(b * 16 + kc) * HW_ + p) * 16 + k16) = h;
}

// ---------------- K0b: weight prep (merged) ----------------
// bid <128: conv_w[co][ci][tap] -> w16c[tap][co][ci]
// bid <224: qkv_w[o][k] -> wF[(kc*384+o)*16+k16]
// else    : attn_w[o][k] -> wP[(kc*128+o)*16+k16]
__global__ __launch_bounds__(256) void wprep_kernel(
    const float* __restrict__ conv_w, const float* __restrict__ qkv_w,
    const float* __restrict__ attn_w, _Float16* __restrict__ w16c,
    _Float16* __restrict__ wF, _Float16* __restrict__ wP)
{
    const int bid = blockIdx.x;
    const int t = threadIdx.x;
    if (bid < 128) {
        const int id = bid * 256 + t;             // co*256+ci
        const int co = id >> 8, ci = id & 255;
        const float* src = conv_w + (size_t)id * 9;
#pragma unroll
        for (int j = 0; j < 9; ++j)
            w16c[(size_t)(j * CCONV_ + co) * CIN_ + ci] = (_Float16)src[j];
    } else if (bid < 224) {
        const int g = (bid - 128) * 256 + t;      // < 24576
        const int o = g >> 6, k0 = (g & 63) * 4;
        const float4 v = *(const float4*)(qkv_w + (size_t)o * CIN_ + k0);
        half4v h; h[0] = (_Float16)v.x; h[1] = (_Float16)v.y;
        h[2] = (_Float16)v.z; h[3] = (_Float16)v.w;
        *(half4v*)(wF + (size_t)((k0 >> 4) * QKVO_ + o) * 16 + (k0 & 15)) = h;
    } else {
        const int g = (bid - 224) * 256 + t;      // < 4096
        const int o = g >> 5, k0 = (g & 31) * 4;
        const float4 v = *(const float4*)(attn_w + (size_t)o * DV_ + k0);
        half4v h; h[0] = (_Float16)v.x; h[1] = (_Float16)v.y;
        h[2] = (_Float16)v.z; h[3] = (_Float16)v.w;
        *(half4v*)(wP + (size_t)((k0 >> 4) * DV_ + o) * 16 + (k0 & 15)) = h;
    }
}

// ---------------- K1: qkv MFMA GEMM (all operands fragment-major, no LDS) ----------------
// Writes Qt/Kt pixel-major [bn][p][c16] and V fragment-major vF[bn][qg][c][q16].
__global__ __launch_bounds__(256) void qkv_kernel(
    const _Float16* __restrict__ xF, const _Float16* __restrict__ wF,
    const float* __restrict__ qkv_b, _Float16* __restrict__ Qt,
    _Float16* __restrict__ Kt, _Float16* __restrict__ vF)
{
    const int pt = blockIdx.x;   // 0..15 (64 pixels)
    const int ot = blockIdx.y;   // 0..5  (64 outputs)
    const int b  = blockIdx.z;
    const int lane = threadIdx.x & 63, w = threadIdx.x >> 6;
    const int l16 = lane & 15, hi = lane >> 4;
    const int p0 = pt * 64;
    const int og = ot * 4 + w;           // 0..23: 0-7 Q, 8-15 K, 16-23 V
    const int o0 = og * 16;

    float4v acc[4];
#pragma unroll
    for (int pg = 0; pg < 4; ++pg) acc[pg] = (float4v){0.f, 0.f, 0.f, 0.f};

    for (int kc = 0; kc < 16; ++kc) {
        const half4v a = *(const half4v*)(wF + (size_t)(kc * QKVO_ + o0 + l16) * 16 + hi * 4);
#pragma unroll
        for (int pg = 0; pg < 4; ++pg) {
            const half4v bf = *(const half4v*)(xF + ((size_t)(b * 16 + kc) * HW_ + p0 + pg * 16 + l16) * 16 + hi * 4);
            acc[pg] = __builtin_amdgcn_mfma_f32_16x16x16f16(a, bf, acc[pg], 0, 0, 0);
        }
    }

    float bias[4];
#pragma unroll
    for (int r = 0; r < 4; ++r) bias[r] = qkv_b[o0 + hi * 4 + r];

    if (og < 16) {
        const float scale = (og < 8) ? 0.25f : 1.0f;    // DKH^-0.5 for Q
        const int n = og & 7;
        _Float16* dst = (og < 8 ? Qt : Kt) + (size_t)(b * NH_ + n) * (HW_ * 16) + hi * 4;
#pragma unroll
        for (int pg = 0; pg < 4; ++pg) {
            const int p = p0 + pg * 16 + l16;
            half4v h;
#pragma unroll
            for (int r = 0; r < 4; ++r) h[r] = (_Float16)((acc[pg][r] + bias[r]) * scale);
            *(half4v*)(dst + (size_t)p * 16) = h;
        }
    } else {
        const int n = og - 16;
        _Float16* Vb = vF + (size_t)(b * NH_ + n) * (64 * 16 * 16);
#pragma unroll
        for (int pg = 0; pg < 4; ++pg) {
            const int qg = pt * 4 + pg;
#pragma unroll
            for (int r = 0; r < 4; ++r)
                Vb[(size_t)(qg * 16 + hi * 4 + r) * 16 + l16] = (_Float16)(acc[pg][r] + bias[r]);
        }
    }
}

// ---------------- K2: fused MFMA attention ----------------
// QK^T swapped-operand (verified R3); V now fragment-major; output written as
// f16 aF[b][pgrp][head][pix16][k16] == proj's B-fragment layout.
__global__ __launch_bounds__(256) void attn_kernel(
    const _Float16* __restrict__ Qt, const _Float16* __restrict__ Kt,
    const _Float16* __restrict__ vF, _Float16* __restrict__ aF)
{
    const int bx = blockIdx.x;                 // ((b*8+n)*4 + pc)
    const int pc = bx & 3;
    const int n  = (bx >> 2) & 7;
    const int b  = bx >> 5;
    const int lane = threadIdx.x & 63, wave = threadIdx.x >> 6;
    const int l16 = lane & 15, lg = lane >> 4;

    const int bn = b * NH_ + n;
    const _Float16* Qh = Qt + (size_t)bn * (HW_ * 16);
    const _Float16* Kh = Kt + (size_t)bn * (HW_ * 16);
    const _Float16* Vh = vF + (size_t)bn * (64 * 16 * 16);

    const int pbase = pc * 256 + wave * 64;

    half4v qf[4];
#pragma unroll
    for (int t = 0; t < 4; ++t)
        qf[t] = *(const half4v*)(Qh + (size_t)(pbase + t * 16 + l16) * 16 + lg * 4);

    float4v o[4];
    float rs[4];
#pragma unroll
    for (int t = 0; t < 4; ++t) { o[t] = (float4v){0.f, 0.f, 0.f, 0.f}; rs[t] = 0.f; }

    const float4v zero = (float4v){0.f, 0.f, 0.f, 0.f};

    for (int q0 = 0; q0 < HW_; q0 += 16) {
        const half4v kf = *(const half4v*)(Kh + (size_t)(q0 + l16) * 16 + lg * 4);
        const half4v vf = *(const half4v*)(Vh + (size_t)((q0 >> 4) * 16 + l16) * 16 + lg * 4);
#pragma unroll
        for (int t = 0; t < 4; ++t) {
            float4v s = __builtin_amdgcn_mfma_f32_16x16x16f16(kf, qf[t], zero, 0, 0, 0);
            const float e0 = __expf(s[0]);
            const float e1 = __expf(s[1]);
            const float e2 = __expf(s[2]);
            const float e3 = __expf(s[3]);
            rs[t] += (e0 + e1) + (e2 + e3);
            half4v pf;
            pf[0] = (_Float16)e0; pf[1] = (_Float16)e1;
            pf[2] = (_Float16)e2; pf[3] = (_Float16)e3;
            o[t] = __builtin_amdgcn_mfma_f32_16x16x16f16(vf, pf, o[t], 0, 0, 0);
        }
    }
#pragma unroll
    for (int t = 0; t < 4; ++t) {
        float r = rs[t];
        r += __shfl_xor(r, 16);
        r += __shfl_xor(r, 32);
        const float inv = 1.0f / r;
        half4v h;
#pragma unroll
        for (int rr = 0; rr < 4; ++rr) h[rr] = (_Float16)(o[t][rr] * inv);
        // aF[b][pgrp][n][pix16][k16], pgrp = (pbase>>4)+t, k16 = lg*4+rr
        *(half4v*)(aF + (((size_t)(b * 64 + (pbase >> 4) + t) * NH_ + n) * 16 + l16) * 16 + lg * 4) = h;
    }
}

// ---------------- K3: attn projection as MFMA GEMM (fragment-major, no LDS) ----------------
__global__ __launch_bounds__(256) void proj_kernel(
    const _Float16* __restrict__ aF, const _Float16* __restrict__ wP,
    const float* __restrict__ attn_b, float* __restrict__ out)
{
    const int pt = blockIdx.x;   // 0..15 (64 pixels)
    const int ot = blockIdx.y;   // 0..1  (64 outputs)
    const int b  = blockIdx.z;
    const int lane = threadIdx.x & 63, w = threadIdx.x >> 6;
    const int l16 = lane & 15, hi = lane >> 4;
    const int p0 = pt * 64;
    const int o0 = ot * 64 + w * 16;

    float4v acc[4];
#pragma unroll
    for (int pg = 0; pg < 4; ++pg) acc[pg] = (float4v){0.f, 0.f, 0.f, 0.f};

    for (int kc = 0; kc < 8; ++kc) {
        const half4v a = *(const half4v*)(wP + (size_t)(kc * DV_ + o0 + l16) * 16 + hi * 4);
#pragma unroll
        for (int pg = 0; pg < 4; ++pg) {
            const half4v bf = *(const half4v*)(aF + (((size_t)(b * 64 + pt * 4 + pg) * NH_ + kc) * 16 + l16) * 16 + hi * 4);
            acc[pg] = __builtin_amdgcn_mfma_f32_16x16x16f16(a, bf, acc[pg], 0, 0, 0);
        }
    }
#pragma unroll
    for (int pg = 0; pg < 4; ++pg) {
        const int p = p0 + pg * 16 + l16;
#pragma unroll
        for (int r = 0; r < 4; ++r) {
            const int o = o0 + hi * 4 + r;
            out[((size_t)(b * COUT_ + CCONV_ + o)) * HW_ + p] = acc[pg][r] + attn_b[o];
        }
    }
}

// ---------------- K4: 3x3 conv as implicit-GEMM MFMA (unchanged, verified R5) ----------------
__global__ __launch_bounds__(256) void conv_kernel(
    const _Float16* __restrict__ xT, const _Float16* __restrict__ w16c,
    const float* __restrict__ conv_b, float* __restrict__ out)
{
    const int strip = blockIdx.x;  // 0..7
    const int cot   = blockIdx.y;  // 0..3
    const int b     = blockIdx.z;
    const int t = threadIdx.x;
    const int lane = t & 63, w = t >> 6;
    const int l16 = lane & 15, hi = lane >> 4;
    const int r0 = strip * 4, co0 = cot * 32;

    __shared__ _Float16 Wl[9 * 32 * 16];    // 9216 B
    __shared__ _Float16 Xs[204 * 16];       // 6528 B

    float4v acc[2][2];
#pragma unroll
    for (int i = 0; i < 2; ++i)
#pragma unroll
        for (int j = 0; j < 2; ++j) acc[i][j] = (float4v){0.f, 0.f, 0.f, 0.f};

    for (int ci0 = 0; ci0 < CIN_; ci0 += 16) {
        __syncthreads();
        for (int i = t; i < 288; i += 256) {
            const int tap = i >> 5, co = i & 31;
            const uint4* s = (const uint4*)(w16c + (size_t)(tap * CCONV_ + co0 + co) * CIN_ + ci0);
            uint4* d = (uint4*)(Wl + i * 16);
            d[0] = s[0]; d[1] = s[1];
        }
        for (int i = t; i < 204; i += 256) {
            const int hr = i / 34, hc = i - hr * 34;
            const int gr = r0 - 1 + hr, gc = hc - 1;
            uint4* d = (uint4*)(Xs + i * 16);
            if (gr >= 0 && gr < H_ && gc >= 0 && gc < W_) {
                const uint4* s = (const uint4*)(xT + (size_t)(b * HW_ + gr * 32 + gc) * CIN_ + ci0);
                d[0] = s[0]; d[1] = s[1];
            } else {
                uint4 z; z.x = z.y = z.z = z.w = 0u;
                d[0] = z; d[1] = z;
            }
        }
        __syncthreads();
#pragma unroll
        for (int kh = 0; kh < 3; ++kh) {
#pragma unroll
            for (int kw = 0; kw < 3; ++kw) {
                const int tap = kh * 3 + kw;
                const half4v a0 = *(const half4v*)(Wl + (tap * 32 + l16) * 16 + hi * 4);
                const half4v a1 = *(const half4v*)(Wl + (tap * 32 + 16 + l16) * 16 + hi * 4);
                const half4v b0 = *(const half4v*)(Xs + ((w + kh) * 34 + l16 + kw) * 16 + hi * 4);
                const half4v b1 = *(const half4v*)(Xs + ((w + kh) * 34 + 16 + l16 + kw) * 16 + hi * 4);
                acc[0][0] = __builtin_amdgcn_mfma_f32_16x16x16f16(a0, b0, acc[0][0], 0, 0, 0);
                acc[0][1] = __builtin_amdgcn_mfma_f32_16x16x16f16(a0, b1, acc[0][1], 0, 0, 0);
                acc[1][0] = __builtin_amdgcn_mfma_f32_16x16x16f16(a1, b0, acc[1][0], 0, 0, 0);
                acc[1][1] = __builtin_amdgcn_mfma_f32_16x16x16f16(a1, b1, acc[1][1], 0, 0, 0);
            }
        }
    }
    const int row = r0 + w;
#pragma unroll
    for (int cog = 0; cog < 2; ++cog)
#pragma unroll
        for (int r = 0; r < 4; ++r) {
            const int co = co0 + cog * 16 + hi * 4 + r;
            const float bias = conv_b[co];
            float* dst = out + (size_t)(b * COUT_ + co) * HW_ + row * 32;
            dst[l16]      = acc[cog][0][r] + bias;
            dst[16 + l16] = acc[cog][1][r] + bias;
        }
}

extern "C" void kernel_launch(void* const* d_in, const int* in_sizes, int n_in,
                              void* d_out, int out_size, void* d_ws, size_t ws_size,
                              hipStream_t stream)
{
    (void)in_sizes; (void)n_in; (void)out_size; (void)ws_size;
    const float* x      = (const float*)d_in[0];
    const float* conv_w = (const float*)d_in[1];
    const float* conv_b = (const float*)d_in[2];
    const float* qkv_w  = (const float*)d_in[3];
    const float* qkv_b  = (const float*)d_in[4];
    const float* attn_w = (const float*)d_in[5];
    const float* attn_b = (const float*)d_in[6];
    float* out = (float*)d_out;

    char* ws = (char*)d_ws;
    _Float16* xT   = (_Float16*)(ws);               // 8,388,608
    _Float16* xF   = (_Float16*)(ws + 8388608);     // 8,388,608 (dead after qkv)
    _Float16* w16c = (_Float16*)(ws + 16777216);    //   589,824
    _Float16* wF   = (_Float16*)(ws + 17367040);    //   196,608
    _Float16* wP   = (_Float16*)(ws + 17563648);    //    32,768
    _Float16* Qt   = (_Float16*)(ws + 17596416);    // 4,194,304
    _Float16* Kt   = (_Float16*)(ws + 21790720);    // 4,194,304
    _Float16* vF   = (_Float16*)(ws + 25985024);    // 4,194,304 (end 30,179,328)
    _Float16* aF   = xF;                            // alias: xF dead once qkv ran

    xt_kernel<<<dim3(32, 8, B_), dim3(256), 0, stream>>>(x, xT, xF);
    wprep_kernel<<<dim3(240), dim3(256), 0, stream>>>(conv_w, qkv_w, attn_w, w16c, wF, wP);
    qkv_kernel<<<dim3(16, 6, B_), dim3(256), 0, stream>>>(xF, wF, qkv_b, Qt, Kt, vF);
    attn_kernel<<<dim3(512), dim3(256), 0, stream>>>(Qt, Kt, vF, aF);
    proj_kernel<<<dim3(16, 2, B_), dim3(256), 0, stream>>>(aF, wP, attn_b, out);
    conv_kernel<<<dim3(8, 4, B_), dim3(256), 0, stream>>>(xT, w16c, conv_b, out);
}

// Round 8
// 177.316 us; speedup vs baseline: 4.1733x; 1.0592x over previous
//
#include <hip/hip_runtime.h>
#include <cstddef>

#define B_ 16
#define CIN_ 256
#define H_ 32
#define W_ 32
#define HW_ 1024
#define COUT_ 256
#define DK_ 128
#define DV_ 128
#define NH_ 8
#define DKH_ 16
#define DVH_ 16
#define CCONV_ 128
#define QKVO_ 384

typedef __attribute__((ext_vector_type(4))) _Float16 half4v;
typedef __attribute__((ext_vector_type(8))) _Float16 half8v;
typedef __attribute__((ext_vector_type(4))) float float4v;

// K32 fragment convention for mfma_f32_16x16x32_f16:
//   lane (l16 = row/col, hi = lane>>4) holds 8 contiguous k: k = hi*8..hi*8+7.
//   Store fragments as [r(16)][k32(32)] halves -> lane reads 16 B at r*64B + hi*16B;
//   the wave's 64 lanes cover one contiguous 1024-B block.

// ---------------- K0: x -> xF[b][kc(8)][pix(1024)][k32(32)] (f16) ----------------
__global__ __launch_bounds__(256) void xt_kernel(
    const float* __restrict__ x, _Float16* __restrict__ xF)
{
    const int pt = blockIdx.x;   // 0..31 pixel tile
    const int ct = blockIdx.y;   // 0..7  ci tile (32 ch)
    const int b  = blockIdx.z;
    __shared__ float T[32][33];
    const int t = threadIdx.x;
    const int c = t & 31, r = t >> 5;
#pragma unroll
    for (int i = 0; i < 4; ++i) {
        const int ci = ct * 32 + r + i * 8;
        T[r + i * 8][c] = x[(size_t)(b * CIN_ + ci) * HW_ + pt * 32 + c];
    }
    __syncthreads();
    const int cq = (t & 7) * 4;      // ci quad within the 32-chunk
    const int pi = t >> 3;           // pixel within tile
    half4v h;
#pragma unroll
    for (int j = 0; j < 4; ++j) h[j] = (_Float16)T[cq + j][pi];
    const int p = pt * 32 + pi;
    *(half4v*)(xF + ((size_t)(b * 8 + ct) * HW_ + p) * 32 + cq) = h;
}

// ---------------- K0b: weight prep (merged, K32 fragment-major) ----------------
// bid <128: conv_w[co][ci][tap] -> wC[((ci>>5)*9+tap)*8 + co>>4][co&15][ci&31]
// bid <224: qkv_w[o][k]  -> wF[(k>>5)*384 + o][k&31]
// else    : attn_w[o][k] -> wP[(k>>5)*128 + o][k&31]
__global__ __launch_bounds__(256) void wprep_kernel(
    const float* __restrict__ conv_w, const float* __restrict__ qkv_w,
    const float* __restrict__ attn_w, _Float16* __restrict__ wC,
    _Float16* __restrict__ wF, _Float16* __restrict__ wP)
{
    const int bid = blockIdx.x;
    const int t = threadIdx.x;
    if (bid < 128) {
        const int id = bid * 256 + t;             // co*256+ci
        const int co = id >> 8, ci = id & 255;
        const float* src = conv_w + (size_t)id * 9;
#pragma unroll
        for (int j = 0; j < 9; ++j)
            wC[(((size_t)(ci >> 5) * 9 + j) * 8 + (co >> 4)) * 512 + (co & 15) * 32 + (ci & 31)]
                = (_Float16)src[j];
    } else if (bid < 224) {
        const int g = (bid - 128) * 256 + t;      // < 24576
        const int o = g >> 6, k0 = (g & 63) * 4;
        const float4 v = *(const float4*)(qkv_w + (size_t)o * CIN_ + k0);
        half4v h; h[0] = (_Float16)v.x; h[1] = (_Float16)v.y;
        h[2] = (_Float16)v.z; h[3] = (_Float16)v.w;
        *(half4v*)(wF + ((size_t)(k0 >> 5) * QKVO_ + o) * 32 + (k0 & 31)) = h;
    } else {
        const int g = (bid - 224) * 256 + t;      // < 4096
        const int o = g >> 5, k0 = (g & 31) * 4;
        const float4 v = *(const float4*)(attn_w + (size_t)o * DV_ + k0);
        half4v h; h[0] = (_Float16)v.x; h[1] = (_Float16)v.y;
        h[2] = (_Float16)v.z; h[3] = (_Float16)v.w;
        *(half4v*)(wP + ((size_t)(k0 >> 5) * DV_ + o) * 32 + (k0 & 31)) = h;
    }
}

// ---------------- K1: qkv MFMA GEMM (K32, fragment-major, no LDS) ----------------
// Writes Qt/Kt pixel-major [bn][p][c16] and V fragment-major vF[bn][qg][c][q16]
// (both consumed by the 16x16x16 attention, unchanged).
__global__ __launch_bounds__(256) void qkv_kernel(
    const _Float16* __restrict__ xF, const _Float16* __restrict__ wF,
    const float* __restrict__ qkv_b, _Float16* __restrict__ Qt,
    _Float16* __restrict__ Kt, _Float16* __restrict__ vF)
{
    const int pt = blockIdx.x;   // 0..15 (64 pixels)
    const int ot = blockIdx.y;   // 0..5  (64 outputs)
    const int b  = blockIdx.z;
    const int lane = threadIdx.x & 63, w = threadIdx.x >> 6;
    const int l16 = lane & 15, hi = lane >> 4;
    const int p0 = pt * 64;
    const int og = ot * 4 + w;           // 0..23: 0-7 Q, 8-15 K, 16-23 V
    const int o0 = og * 16;

    float4v acc[4];
#pragma unroll
    for (int pg = 0; pg < 4; ++pg) acc[pg] = (float4v){0.f, 0.f, 0.f, 0.f};

    for (int kc = 0; kc < 8; ++kc) {
        const half8v a = *(const half8v*)(wF + ((size_t)kc * QKVO_ + o0 + l16) * 32 + hi * 8);
#pragma unroll
        for (int pg = 0; pg < 4; ++pg) {
            const half8v bf = *(const half8v*)(xF + ((size_t)(b * 8 + kc) * HW_ + p0 + pg * 16 + l16) * 32 + hi * 8);
            acc[pg] = __builtin_amdgcn_mfma_f32_16x16x32_f16(a, bf, acc[pg], 0, 0, 0);
        }
    }

    float bias[4];
#pragma unroll
    for (int r = 0; r < 4; ++r) bias[r] = qkv_b[o0 + hi * 4 + r];

    if (og < 16) {
        const float scale = (og < 8) ? 0.25f : 1.0f;    // DKH^-0.5 for Q
        const int n = og & 7;
        _Float16* dst = (og < 8 ? Qt : Kt) + (size_t)(b * NH_ + n) * (HW_ * 16) + hi * 4;
#pragma unroll
        for (int pg = 0; pg < 4; ++pg) {
            const int p = p0 + pg * 16 + l16;
            half4v h;
#pragma unroll
            for (int r = 0; r < 4; ++r) h[r] = (_Float16)((acc[pg][r] + bias[r]) * scale);
            *(half4v*)(dst + (size_t)p * 16) = h;
        }
    } else {
        const int n = og - 16;
        _Float16* Vb = vF + (size_t)(b * NH_ + n) * (64 * 16 * 16);
#pragma unroll
        for (int pg = 0; pg < 4; ++pg) {
            const int qg = pt * 4 + pg;
#pragma unroll
            for (int r = 0; r < 4; ++r)
                Vb[(size_t)(qg * 16 + hi * 4 + r) * 16 + l16] = (_Float16)(acc[pg][r] + bias[r]);
        }
    }
}

// ---------------- K2: fused MFMA attention (16x16x16 path verified R3/R7) ----------------
// Only change vs R7: output store index -> K32 layout for proj:
// aF[b][pgrp(64)][npair(4)][pix16][k32] with k32 = (n&1)*16 + c.
__global__ __launch_bounds__(256) void attn_kernel(
    const _Float16* __restrict__ Qt, const _Float16* __restrict__ Kt,
    const _Float16* __restrict__ vF, _Float16* __restrict__ aF)
{
    const int bx = blockIdx.x;                 // ((b*8+n)*4 + pc)
    const int pc = bx & 3;
    const int n  = (bx >> 2) & 7;
    const int b  = bx >> 5;
    const int lane = threadIdx.x & 63, wave = threadIdx.x >> 6;
    const int l16 = lane & 15, lg = lane >> 4;

    const int bn = b * NH_ + n;
    const _Float16* Qh = Qt + (size_t)bn * (HW_ * 16);
    const _Float16* Kh = Kt + (size_t)bn * (HW_ * 16);
    const _Float16* Vh = vF + (size_t)bn * (64 * 16 * 16);

    const int pbase = pc * 256 + wave * 64;

    half4v qf[4];
#pragma unroll
    for (int t = 0; t < 4; ++t)
        qf[t] = *(const half4v*)(Qh + (size_t)(pbase + t * 16 + l16) * 16 + lg * 4);

    float4v o[4];
    float rs[4];
#pragma unroll
    for (int t = 0; t < 4; ++t) { o[t] = (float4v){0.f, 0.f, 0.f, 0.f}; rs[t] = 0.f; }

    const float4v zero = (float4v){0.f, 0.f, 0.f, 0.f};

    for (int q0 = 0; q0 < HW_; q0 += 16) {
        const half4v kf = *(const half4v*)(Kh + (size_t)(q0 + l16) * 16 + lg * 4);
        const half4v vf = *(const half4v*)(Vh + (size_t)((q0 >> 4) * 16 + l16) * 16 + lg * 4);
#pragma unroll
        for (int t = 0; t < 4; ++t) {
            float4v s = __builtin_amdgcn_mfma_f32_16x16x16f16(kf, qf[t], zero, 0, 0, 0);
            const float e0 = __expf(s[0]);
            const float e1 = __expf(s[1]);
            const float e2 = __expf(s[2]);
            const float e3 = __expf(s[3]);
            rs[t] += (e0 + e1) + (e2 + e3);
            half4v pf;
            pf[0] = (_Float16)e0; pf[1] = (_Float16)e1;
            pf[2] = (_Float16)e2; pf[3] = (_Float16)e3;
            o[t] = __builtin_amdgcn_mfma_f32_16x16x16f16(vf, pf, o[t], 0, 0, 0);
        }
    }
#pragma unroll
    for (int t = 0; t < 4; ++t) {
        float r = rs[t];
        r += __shfl_xor(r, 16);
        r += __shfl_xor(r, 32);
        const float inv = 1.0f / r;
        half4v h;
#pragma unroll
        for (int rr = 0; rr < 4; ++rr) h[rr] = (_Float16)(o[t][rr] * inv);
        // K32 layout: [b][pgrp][n>>1][p16][ (n&1)*16 + lg*4 ]
        *(half4v*)(aF + (((size_t)(b * 64 + (pbase >> 4) + t) * 4 + (n >> 1)) * 16 + l16) * 32
                      + (n & 1) * 16 + lg * 4) = h;
    }
}

// ---------------- K3: attn projection MFMA GEMM (K32, no LDS) ----------------
__global__ __launch_bounds__(256) void proj_kernel(
    const _Float16* __restrict__ aF, const _Float16* __restrict__ wP,
    const float* __restrict__ attn_b, float* __restrict__ out)
{
    const int pt = blockIdx.x;   // 0..15 (64 pixels)
    const int ot = blockIdx.y;   // 0..1  (64 outputs)
    const int b  = blockIdx.z;
    const int lane = threadIdx.x & 63, w = threadIdx.x >> 6;
    const int l16 = lane & 15, hi = lane >> 4;
    const int p0 = pt * 64;
    const int o0 = ot * 64 + w * 16;

    float4v acc[4];
#pragma unroll
    for (int pg = 0; pg < 4; ++pg) acc[pg] = (float4v){0.f, 0.f, 0.f, 0.f};

    for (int kc = 0; kc < 4; ++kc) {
        const half8v a = *(const half8v*)(wP + ((size_t)kc * DV_ + o0 + l16) * 32 + hi * 8);
#pragma unroll
        for (int pg = 0; pg < 4; ++pg) {
            const half8v bf = *(const half8v*)(aF + (((size_t)(b * 64 + pt * 4 + pg) * 4 + kc) * 16 + l16) * 32 + hi * 8);
            acc[pg] = __builtin_amdgcn_mfma_f32_16x16x32_f16(a, bf, acc[pg], 0, 0, 0);
        }
    }
#pragma unroll
    for (int pg = 0; pg < 4; ++pg) {
        const int p = p0 + pg * 16 + l16;
#pragma unroll
        for (int r = 0; r < 4; ++r) {
            const int o = o0 + hi * 4 + r;
            out[((size_t)(b * COUT_ + CCONV_ + o)) * HW_ + p] = acc[pg][r] + attn_b[o];
        }
    }
}

// ---------------- K4: 3x3 conv, LDS-free implicit GEMM, K32 MFMA ----------------
// Block: 4 waves (wc,wp 2x2); wave = 32 co x 32 px (one output row).
// A frags from wC (L2-resident), B frags directly from xF; halo via
// wave-uniform row skip + per-lane column zeroing.
__global__ __launch_bounds__(256) void conv_kernel(
    const _Float16* __restrict__ xF, const _Float16* __restrict__ wC,
    const float* __restrict__ conv_b, float* __restrict__ out)
{
    const int rp = blockIdx.x;     // 0..15 row pair
    const int ch = blockIdx.y;     // 0..1  co half
    const int b  = blockIdx.z;
    const int t = threadIdx.x;
    const int lane = t & 63, w = t >> 6;
    const int wc = w & 1, wp = w >> 1;
    const int l16 = lane & 15, hi = lane >> 4;
    const int r = rp * 2 + wp;           // output row
    const int coc0 = ch * 4 + wc * 2;    // base 16-co chunk (2 chunks per wave)

    const bool lane0bad  = (l16 == 0);   // col -1 at kw=0, frag0
    const bool lane15bad = (l16 == 15);  // col 32 at kw=2, frag1
    const half8v z = {0, 0, 0, 0, 0, 0, 0, 0};

    float4v acc[2][2];
#pragma unroll
    for (int i = 0; i < 2; ++i)
#pragma unroll
        for (int j = 0; j < 2; ++j) acc[i][j] = (float4v){0.f, 0.f, 0.f, 0.f};

    for (int kc = 0; kc < 8; ++kc) {
        const _Float16* xk = xF + ((size_t)(b * 8 + kc) * HW_ + r * 32) * 32 + l16 * 32 + hi * 8;
        const _Float16* ab = wC + ((size_t)(kc * 9) * 8 + coc0) * 512 + l16 * 32 + hi * 8;
#pragma unroll
        for (int kh = 0; kh < 3; ++kh) {
            const int rr = r + kh - 1;
            if ((unsigned)rr >= 32u) continue;   // zero-pad row: contribution is 0
#pragma unroll
            for (int kw = 0; kw < 3; ++kw) {
                const _Float16* a = ab + (size_t)((kh * 3 + kw) * 8) * 512;
                const half8v a0 = *(const half8v*)(a);
                const half8v a1 = *(const half8v*)(a + 512);
                const int sh = ((kh - 1) * 32 + (kw - 1)) * 32;   // halves
                half8v b0 = *(const half8v*)(xk + sh);
                half8v b1 = *(const half8v*)(xk + sh + 16 * 32);
                if (kw == 0) b0 = lane0bad  ? z : b0;
                if (kw == 2) b1 = lane15bad ? z : b1;
                acc[0][0] = __builtin_amdgcn_mfma_f32_16x16x32_f16(a0, b0, acc[0][0], 0, 0, 0);
                acc[0][1] = __builtin_amdgcn_mfma_f32_16x16x32_f16(a0, b1, acc[0][1], 0, 0, 0);
                acc[1][0] = __builtin_amdgcn_mfma_f32_16x16x32_f16(a1, b0, acc[1][0], 0, 0, 0);
                acc[1][1] = __builtin_amdgcn_mfma_f32_16x16x32_f16(a1, b1, acc[1][1], 0, 0, 0);
            }
        }
    }
#pragma unroll
    for (int cog = 0; cog < 2; ++cog)
#pragma unroll
        for (int rr = 0; rr < 4; ++rr) {
            const int co = (coc0 + cog) * 16 + hi * 4 + rr;
            const float bias = conv_b[co];
            float* dst = out + (size_t)(b * COUT_ + co) * HW_ + r * 32;
            dst[l16]      = acc[cog][0][rr] + bias;
            dst[16 + l16] = acc[cog][1][rr] + bias;
        }
}

extern "C" void kernel_launch(void* const* d_in, const int* in_sizes, int n_in,
                              void* d_out, int out_size, void* d_ws, size_t ws_size,
                              hipStream_t stream)
{
    (void)in_sizes; (void)n_in; (void)out_size; (void)ws_size;
    const float* x      = (const float*)d_in[0];
    const float* conv_w = (const float*)d_in[1];
    const float* conv_b = (const float*)d_in[2];
    const float* qkv_w  = (const float*)d_in[3];
    const float* qkv_b  = (const float*)d_in[4];
    const float* attn_w = (const float*)d_in[5];
    const float* attn_b = (const float*)d_in[6];
    float* out = (float*)d_out;

    char* ws = (char*)d_ws;
    // xF at +4096 so the conv halo's lane-0 read at base-64B stays inside d_ws.
    _Float16* xF = (_Float16*)(ws + 4096);          // 8,388,608
    _Float16* wC = (_Float16*)(ws + 8392704);       //   589,824
    _Float16* wF = (_Float16*)(ws + 8982528);       //   196,608
    _Float16* wP = (_Float16*)(ws + 9179136);       //    32,768
    _Float16* Qt = (_Float16*)(ws + 9211904);       // 4,194,304
    _Float16* Kt = (_Float16*)(ws + 13406208);      // 4,194,304
    _Float16* vF = (_Float16*)(ws + 17600512);      // 4,194,304
    _Float16* aF = (_Float16*)(ws + 21794816);      // 4,194,304 (end 25,989,120)

    xt_kernel<<<dim3(32, 8, B_), dim3(256), 0, stream>>>(x, xF);
    wprep_kernel<<<dim3(240), dim3(256), 0, stream>>>(conv_w, qkv_w, attn_w, wC, wF, wP);
    qkv_kernel<<<dim3(16, 6, B_), dim3(256), 0, stream>>>(xF, wF, qkv_b, Qt, Kt, vF);
    attn_kernel<<<dim3(512), dim3(256), 0, stream>>>(Qt, Kt, vF, aF);
    proj_kernel<<<dim3(16, 2, B_), dim3(256), 0, stream>>>(aF, wP, attn_b, out);
    conv_kernel<<<dim3(16, 2, B_), dim3(256), 0, stream>>>(xF, wC, conv_b, out);
}